// Round 5
// baseline (1149.102 us; speedup 1.0000x reference)
//
#include <hip/hip_runtime.h>
#include <hip/hip_fp16.h>
#include <float.h>

#define M_ROWS 32768
#define E_DIM  512
#define N_E    8192

#define BM 128
#define BN 128
#define BK 32
#define NQ 4                    // quarters of the e-range
#define EQ (N_E / NQ)           // 2048 codes per quarter

typedef __attribute__((ext_vector_type(8))) _Float16 half8;
typedef __attribute__((ext_vector_type(4))) float f32x4;

__device__ inline void gl_lds16(const void* g, void* l) {
    __builtin_amdgcn_global_load_lds(
        (const __attribute__((address_space(1))) unsigned int*)g,
        (__attribute__((address_space(3))) unsigned int*)l, 16, 0, 0);
}

// ---------------- fp32 -> fp16 (RTNE) ----------------
__global__ __launch_bounds__(256) void f16_cast_kernel(const float* __restrict__ X,
                                                       ushort* __restrict__ H,
                                                       int n4) {
    int i = blockIdx.x * 256 + threadIdx.x;
    if (i >= n4) return;
    float4 v = ((const float4*)X)[i];
    float c[4] = {v.x, v.y, v.z, v.w};
    ushort hh[4];
    #pragma unroll
    for (int j = 0; j < 4; j++) {
        __half hb = __float2half(c[j]);
        hh[j] = *(ushort*)&hb;
    }
    ushort4 h = {hh[0], hh[1], hh[2], hh[3]};
    ((ushort4*)H)[i] = h;
}

// ---------------- wnorm[e] = sum_k W[e][k]^2 (fp32, exact) ----------------
__global__ __launch_bounds__(256) void wnorm_kernel(const float* __restrict__ W,
                                                    float* __restrict__ wnorm) {
    int wave_id = (int)((blockIdx.x * blockDim.x + threadIdx.x) >> 6);
    int lane = threadIdx.x & 63;
    if (wave_id >= N_E) return;
    const float* row = W + (size_t)wave_id * E_DIM;
    float4 v0 = *(const float4*)(row + lane * 4);
    float4 v1 = *(const float4*)(row + 256 + lane * 4);
    float s = v0.x*v0.x + v0.y*v0.y + v0.z*v0.z + v0.w*v0.w
            + v1.x*v1.x + v1.y*v1.y + v1.z*v1.z + v1.w*v1.w;
    #pragma unroll
    for (int off = 32; off; off >>= 1) s += __shfl_down(s, off);
    if (lane == 0) wnorm[wave_id] = s;
}

struct Top2 { float v0, v1; int i0, i1; };

__device__ inline Top2 merge2(Top2 A, Top2 B) {
    bool af = (A.v0 < B.v0) || (A.v0 == B.v0 && A.i0 < B.i0);
    float Wv1 = af ? A.v1 : B.v1; int Wi1 = af ? A.i1 : B.i1;
    float Lv0 = af ? B.v0 : A.v0; int Li0 = af ? B.i0 : A.i0;
    bool s2 = (Wv1 < Lv0) || (Wv1 == Lv0 && Wi1 < Li0);
    Top2 R;
    R.v0 = af ? A.v0 : B.v0; R.i0 = af ? A.i0 : B.i0;
    R.v1 = s2 ? Wv1 : Lv0;   R.i1 = s2 ? Wi1 : Li0;
    return R;
}

// ---------------- fp16 MFMA screen (K=512) + per-row top-2 per QUARTER ----------------
// Screen semantics IDENTICAL to the passing R4 config (fp16 scores, top-2 per
// 2048-code quarter, exact fp32 rescore of 8 candidates). Rewritten execution:
// 8 waves (512 thr) with 64x32 wave tiles -> acc[4][2]=32 VGPR, no spill at the
// 128-VGPR cap; 2-phase double-buffered LDS pipeline, ONE barrier per K-step
// (stage(next,buf^1) -> compute(buf) -> barrier), hiding global-load latency
// under ds_read+MFMA+fold.
__global__ __launch_bounds__(512, 4) void argmin_mfma(
        const ushort* __restrict__ Zh, const ushort* __restrict__ Wh,
        const float* __restrict__ wnorm, int* __restrict__ cand) {
    __shared__ __align__(16) ushort As[2][BM * BK];   // 2 x 8 KB
    __shared__ __align__(16) ushort Bs[2][BN * BK];   // 2 x 8 KB
    __shared__ float4 SmTop[BM][4];                   // 8 KB

    const int t = threadIdx.x;
    const int lane = t & 63;
    const int wid = t >> 6;            // 0..7
    const int wave_m = wid >> 2;       // 0..1 (64-row chunk)
    const int wave_n = wid & 3;        // 0..3 (32-col chunk)
    const int l15 = lane & 15, l4 = lane >> 4;

    // chunked XCD remap (1024 blocks, 8 XCDs, 128-block chunks; bijective)
    const int id = blockIdx.x;
    const int orig = (id & 7) * 128 + (id >> 3);
    const int quarter = orig >> 8;     // 2 XCDs per quarter
    const int rowblk = orig & 255;
    const int row0 = rowblk * BM;
    const int ebase = quarter * EQ;

    // staging: 512 threads x 16B = 8 KB = one full A (or B) tile per round.
    // thread t covers row srow = t>>2, k-chunk (t&3)*8.
    const int srow = t >> 2;
    const int kq = (t & 3) * 8;
    const ushort* Abase = Zh + (size_t)(row0 + srow) * E_DIM + kq;
    const ushort* Bbase = Wh + (size_t)(ebase + srow) * E_DIM + kq;
    char* aL0 = (char*)As[0] + t * 16;  char* aL1 = (char*)As[1] + t * 16;
    char* bL0 = (char*)Bs[0] + t * 16;  char* bL1 = (char*)Bs[1] + t * 16;

    // per-thread top2 over 16 row-slots q=mi*4+r; row = wave_m*64+mi*16+l4*4+r
    float v0[16], v1[16];
    int i0[16], i1[16];
    #pragma unroll
    for (int q = 0; q < 16; q++) { v0[q] = FLT_MAX; v1[q] = FLT_MAX; i0[q] = 0; i1[q] = 0; }

    // step s in [0,256): e0-tile = s>>4, k-step = s&15.
    #define STAGE(s, AL, BL)  do {                                               \
        int _s = (s);                                                            \
        gl_lds16(Abase + (_s & 15) * BK, (AL));                                  \
        gl_lds16(Bbase + ((size_t)(_s >> 4) << 16) + (_s & 15) * BK, (BL));      \
    } while (0)

    const ushort* ab0 = As[0] + (wave_m * 64 + l15) * BK + l4 * 8;
    const ushort* bb0 = Bs[0] + (wave_n * 32 + l15) * BK + l4 * 8;
    const ushort* ab1 = As[1] + (wave_m * 64 + l15) * BK + l4 * 8;
    const ushort* bb1 = Bs[1] + (wave_n * 32 + l15) * BK + l4 * 8;

    f32x4 acc[4][2];

    #define COMPUTE(AB, BB) do {                                                 \
        half8 a_[4], b_[2];                                                      \
        _Pragma("unroll")                                                        \
        for (int mi = 0; mi < 4; mi++) a_[mi] = *(const half8*)((AB) + mi * 16 * BK); \
        _Pragma("unroll")                                                        \
        for (int ni = 0; ni < 2; ni++) b_[ni] = *(const half8*)((BB) + ni * 16 * BK); \
        _Pragma("unroll")                                                        \
        for (int mi = 0; mi < 4; mi++)                                           \
            _Pragma("unroll")                                                    \
            for (int ni = 0; ni < 2; ni++)                                       \
                acc[mi][ni] = __builtin_amdgcn_mfma_f32_16x16x32_f16(a_[mi], b_[ni], acc[mi][ni], 0, 0, 0); \
    } while (0)

    STAGE(0, aL0, bL0);
    __syncthreads();                       // drains vmcnt -> buf0 ready

    for (int e0 = 0; e0 < 16; e0++) {
        #pragma unroll
        for (int mi = 0; mi < 4; mi++)
            #pragma unroll
            for (int ni = 0; ni < 2; ni++)
                acc[mi][ni] = (f32x4){0.f, 0.f, 0.f, 0.f};

        for (int p = 0; p < 8; p++) {
            const int s = e0 * 16 + p * 2;
            STAGE(s + 1, aL1, bL1);        // fill buf1 while computing buf0
            COMPUTE(ab0, bb0);
            __syncthreads();               // drain: buf1 ready, buf0 reads done
            if (s + 2 < 256) STAGE(s + 2, aL0, bL0);
            COMPUTE(ab1, bb1);
            if (p == 7) {
                // fold: score = wnorm[e] - 2*dot; D: col=lane&15, row=(lane>>4)*4+reg
                #pragma unroll
                for (int ni = 0; ni < 2; ni++) {
                    int col = ebase + e0 * BN + wave_n * 32 + ni * 16 + l15;
                    float wn = wnorm[col];
                    #pragma unroll
                    for (int mi = 0; mi < 4; mi++)
                        #pragma unroll
                        for (int r = 0; r < 4; r++) {
                            float sc = fmaf(-2.0f, acc[mi][ni][r], wn);
                            int q = mi * 4 + r;
                            if (sc < v0[q])      { v1[q] = v0[q]; i1[q] = i0[q]; v0[q] = sc; i0[q] = col; }
                            else if (sc < v1[q]) { v1[q] = sc; i1[q] = col; }
                        }
                }
            }
            __syncthreads();               // drain: buf0 ready, buf1 reads done
        }
    }

    // 16-lane top2 butterfly (lanes sharing a row), then cross-wave_n merge via LDS
    #pragma unroll
    for (int mi = 0; mi < 4; mi++)
        #pragma unroll
        for (int r = 0; r < 4; r++) {
            int q = mi * 4 + r;
            Top2 T = {v0[q], v1[q], i0[q], i1[q]};
            #pragma unroll
            for (int mk = 1; mk <= 8; mk <<= 1) {
                Top2 O;
                O.v0 = __shfl_xor(T.v0, mk); O.v1 = __shfl_xor(T.v1, mk);
                O.i0 = __shfl_xor(T.i0, mk); O.i1 = __shfl_xor(T.i1, mk);
                T = merge2(T, O);
            }
            if (l15 == 0) {
                int rl = wave_m * 64 + mi * 16 + l4 * 4 + r;
                SmTop[rl][wave_n] = make_float4(T.v0, __int_as_float(T.i0), T.v1, __int_as_float(T.i1));
            }
        }
    __syncthreads();
    if (t < BM) {
        Top2 q[4];
        #pragma unroll
        for (int j = 0; j < 4; j++) {
            float4 F = SmTop[t][j];
            q[j].v0 = F.x; q[j].i0 = __float_as_int(F.y);
            q[j].v1 = F.z; q[j].i1 = __float_as_int(F.w);
        }
        Top2 T = merge2(merge2(q[0], q[1]), merge2(q[2], q[3]));
        cand[(size_t)(row0 + t) * (2 * NQ) + quarter * 2 + 0] = T.i0;
        cand[(size_t)(row0 + t) * (2 * NQ) + quarter * 2 + 1] = T.i1;
    }
    #undef STAGE
    #undef COMPUTE
}

// ---------------- fp32 rescore of 8 candidates + gather z_q + loss partial ----------------
__global__ __launch_bounds__(256) void rescore_gather_loss(
        const float* __restrict__ Z, const float* __restrict__ W,
        const float* __restrict__ wnorm, const int* __restrict__ cand,
        float* __restrict__ out, float* __restrict__ partials) {
    const int n = blockIdx.x;
    const int t = threadIdx.x;
    const int lane = t & 63, wv = t >> 6;
    int c[8];
    #pragma unroll
    for (int j = 0; j < 8; j++) c[j] = cand[(size_t)n * 8 + j];
    float2 zv = ((const float2*)(Z + (size_t)n * E_DIM))[t];
    float2 wvv[8];
    #pragma unroll
    for (int j = 0; j < 8; j++)
        wvv[j] = ((const float2*)(W + (size_t)c[j] * E_DIM))[t];
    __shared__ float red[4][8];
    #pragma unroll
    for (int j = 0; j < 8; j++) {
        float s = zv.x * wvv[j].x + zv.y * wvv[j].y;
        #pragma unroll
        for (int off = 32; off; off >>= 1) s += __shfl_down(s, off);
        if (lane == 0) red[wv][j] = s;
    }
    __syncthreads();
    float best = FLT_MAX; int bj = 0, bc = 0x7fffffff;
    #pragma unroll
    for (int j = 0; j < 8; j++) {
        float d = red[0][j] + red[1][j] + red[2][j] + red[3][j];
        float s = wnorm[c[j]] - 2.0f * d;
        if (s < best || (s == best && c[j] < bc)) { best = s; bj = j; bc = c[j]; }
    }
    float2 wq = wvv[0];                 // static-index select (rule #20)
    #pragma unroll
    for (int j = 1; j < 8; j++) if (bj == j) wq = wvv[j];
    ((float2*)(out + 1 + (size_t)n * E_DIM))[t] = wq;   // z_q_st == z_q numerically
    float d0 = wq.x - zv.x, d1 = wq.y - zv.y;
    float sl = d0 * d0 + d1 * d1;
    #pragma unroll
    for (int off = 32; off; off >>= 1) sl += __shfl_down(sl, off);
    __shared__ float red2[4];
    if (lane == 0) red2[wv] = sl;
    __syncthreads();
    if (t == 0) {
        partials[n] = red2[0] + red2[1] + red2[2] + red2[3];
        out[1 + (size_t)M_ROWS * E_DIM + n] = (float)bc;
    }
}

// ---------------- deterministic final loss reduction ----------------
__global__ __launch_bounds__(256) void loss_reduce_kernel(const float* __restrict__ partials,
                                                          float* __restrict__ out) {
    const int t = threadIdx.x;
    float s = 0.0f;
    for (int i = t; i < M_ROWS; i += 256) s += partials[i];
    #pragma unroll
    for (int off = 32; off; off >>= 1) s += __shfl_down(s, off);
    __shared__ float red[4];
    if ((t & 63) == 0) red[t >> 6] = s;
    __syncthreads();
    if (t == 0) {
        float total = red[0] + red[1] + red[2] + red[3];
        out[0] = 2.0f * total / ((float)M_ROWS * (float)E_DIM);  // beta=1 collapses
    }
}

extern "C" void kernel_launch(void* const* d_in, const int* in_sizes, int n_in,
                              void* d_out, int out_size, void* d_ws, size_t ws_size,
                              hipStream_t stream) {
    const float* Z = (const float*)d_in[0];
    const float* W = (const float*)d_in[1];
    float* out = (float*)d_out;

    char* p = (char*)d_ws;
    ushort* Zh = (ushort*)p;      p += (size_t)M_ROWS * E_DIM * 2;
    ushort* Wh = (ushort*)p;      p += (size_t)N_E * E_DIM * 2;
    float* wnorm = (float*)p;     p += (size_t)N_E * 4;
    int* cand = (int*)p;          p += (size_t)M_ROWS * 8 * 4;
    float* partials = (float*)p;  p += (size_t)M_ROWS * 4;

    f16_cast_kernel<<<(M_ROWS * E_DIM / 4 + 255) / 256, 256, 0, stream>>>(Z, Zh, M_ROWS * E_DIM / 4);
    f16_cast_kernel<<<(N_E * E_DIM / 4 + 255) / 256, 256, 0, stream>>>(W, Wh, N_E * E_DIM / 4);
    wnorm_kernel<<<N_E / 4, 256, 0, stream>>>(W, wnorm);
    argmin_mfma<<<NQ * (M_ROWS / BM), 512, 0, stream>>>(Zh, Wh, wnorm, cand);
    rescore_gather_loss<<<M_ROWS, 256, 0, stream>>>(Z, W, wnorm, cand, out, partials);
    loss_reduce_kernel<<<1, 256, 0, stream>>>(partials, out);
}

// Round 6
// 912.107 us; speedup vs baseline: 1.2598x; 1.2598x over previous
//
#include <hip/hip_runtime.h>
#include <hip/hip_fp16.h>
#include <float.h>

#define M_ROWS 32768
#define E_DIM  512
#define N_E    8192

#define BM 64
#define BN 128
#define BK 32
#define NQ 4                    // quarters of the e-range
#define EQ (N_E / NQ)           // 2048 codes per quarter

typedef __attribute__((ext_vector_type(8))) _Float16 half8;
typedef __attribute__((ext_vector_type(4))) float f32x4;

__device__ inline void gl_lds16(const void* g, void* l) {
    __builtin_amdgcn_global_load_lds(
        (const __attribute__((address_space(1))) unsigned int*)g,
        (__attribute__((address_space(3))) unsigned int*)l, 16, 0, 0);
}

// ---------------- fp32 -> fp16 (RTNE) ----------------
__global__ __launch_bounds__(256) void f16_cast_kernel(const float* __restrict__ X,
                                                       ushort* __restrict__ H,
                                                       int n4) {
    int i = blockIdx.x * 256 + threadIdx.x;
    if (i >= n4) return;
    float4 v = ((const float4*)X)[i];
    float c[4] = {v.x, v.y, v.z, v.w};
    ushort hh[4];
    #pragma unroll
    for (int j = 0; j < 4; j++) {
        __half hb = __float2half(c[j]);
        hh[j] = *(ushort*)&hb;
    }
    ushort4 h = {hh[0], hh[1], hh[2], hh[3]};
    ((ushort4*)H)[i] = h;
}

// ---------------- wnorm[e] = sum_k W[e][k]^2 (fp32, exact) ----------------
__global__ __launch_bounds__(256) void wnorm_kernel(const float* __restrict__ W,
                                                    float* __restrict__ wnorm) {
    int wave_id = (int)((blockIdx.x * blockDim.x + threadIdx.x) >> 6);
    int lane = threadIdx.x & 63;
    if (wave_id >= N_E) return;
    const float* row = W + (size_t)wave_id * E_DIM;
    float4 v0 = *(const float4*)(row + lane * 4);
    float4 v1 = *(const float4*)(row + 256 + lane * 4);
    float s = v0.x*v0.x + v0.y*v0.y + v0.z*v0.z + v0.w*v0.w
            + v1.x*v1.x + v1.y*v1.y + v1.z*v1.z + v1.w*v1.w;
    #pragma unroll
    for (int off = 32; off; off >>= 1) s += __shfl_down(s, off);
    if (lane == 0) wnorm[wave_id] = s;
}

struct Top2 { float v0, v1; int i0, i1; };

__device__ inline Top2 merge2(Top2 A, Top2 B) {
    bool af = (A.v0 < B.v0) || (A.v0 == B.v0 && A.i0 < B.i0);
    float Wv1 = af ? A.v1 : B.v1; int Wi1 = af ? A.i1 : B.i1;
    float Lv0 = af ? B.v0 : A.v0; int Li0 = af ? B.i0 : A.i0;
    bool s2 = (Wv1 < Lv0) || (Wv1 == Lv0 && Wi1 < Li0);
    Top2 R;
    R.v0 = af ? A.v0 : B.v0; R.i0 = af ? A.i0 : B.i0;
    R.v1 = s2 ? Wv1 : Lv0;   R.i1 = s2 ? Wi1 : Li0;
    return R;
}

// ---------------- fp16 MFMA screen (K=512) + per-row top-2 per QUARTER ----------------
// Screen semantics identical to the PASSING R4 config. Execution changes:
//  * 256 thr / launch_bounds(256,2): 128-VGPR budget; wave-tile 32x64 ->
//    acc[2][4]=32 VGPR + top2 over 8 row-slots=32 VGPR -> ~115 live, NO SPILL.
//  * T2 XOR swizzle, rule-#21 compliant: LDS dest linear for global_load_lds,
//    global source pre-swizzled, fragment read applies the same involution
//    (16B k-chunk index ^= (row>>1)&3) -> ds_read_b128 2-way aliasing only.
//  * 2-phase double-buffer, one barrier per K-step (unchanged from R5).
__global__ __launch_bounds__(256, 2) void argmin_mfma(
        const ushort* __restrict__ Zh, const ushort* __restrict__ Wh,
        const float* __restrict__ wnorm, int* __restrict__ cand) {
    __shared__ __align__(16) ushort As[2][BM * BK];   // 2 x 4 KB
    __shared__ __align__(16) ushort Bs[2][BN * BK];   // 2 x 8 KB
    __shared__ float4 SmTop[BM][2];                   // 2 KB

    const int t = threadIdx.x;
    const int lane = t & 63;
    const int wid = t >> 6;            // 0..3
    const int wave_m = wid >> 1;       // 0..1 (32-row chunk)
    const int wave_n = wid & 1;        // 0..1 (64-col chunk)
    const int l15 = lane & 15, l4 = lane >> 4;

    // chunked XCD remap (2048 blocks, 8 XCDs, 256-block chunks; bijective).
    // 2 XCDs per quarter -> 2MB W panel L2-resident, lockstep streaming.
    const int id = blockIdx.x;
    const int orig = (id & 7) * 256 + (id >> 3);
    const int quarter = orig >> 9;
    const int rowblk = orig & 511;
    const int row0 = rowblk * BM;
    const int ebase = quarter * EQ;

    // staging (per 32-wide K-step): A tile 64x32 = 256 16B-chunks (1/thread),
    // B tile 128x32 = 512 chunks (2/thread). LDS chunk t holds row t>>2,
    // k-chunk ((t&3) XOR ((row>>1)&3)) -- swizzle applied on the GLOBAL side.
    const int srow = t >> 2;
    const int akc = ((t & 3) ^ ((t >> 3) & 3)) * 8;              // elements
    const int brow1 = 64 + srow;
    const int bkc1 = ((t & 3) ^ ((brow1 >> 1) & 3)) * 8;
    const ushort* AbaseS = Zh + (size_t)(row0 + srow) * E_DIM + akc;
    const ushort* Bbase0 = Wh + (size_t)(ebase + srow) * E_DIM + akc;   // row<64: same xor as A
    const ushort* Bbase1 = Wh + (size_t)(ebase + brow1) * E_DIM + bkc1;
    char* aL0 = (char*)As[0] + t * 16;  char* aL1 = (char*)As[1] + t * 16;
    char* bL0a = (char*)Bs[0] + t * 16; char* bL0b = (char*)Bs[0] + 4096 + t * 16;
    char* bL1a = (char*)Bs[1] + t * 16; char* bL1b = (char*)Bs[1] + 4096 + t * 16;

    // per-thread top2 over 8 row-slots q=mi*4+r; row = wave_m*32+mi*16+l4*4+r
    float v0[8], v1[8];
    int i0[8], i1[8];
    #pragma unroll
    for (int q = 0; q < 8; q++) { v0[q] = FLT_MAX; v1[q] = FLT_MAX; i0[q] = 0; i1[q] = 0; }

    // step s in [0,256): e0-tile = s>>4 (128 codes), k-step = s&15 (32 elems)
    #define STAGE(s, AL, BLa, BLb)  do {                                         \
        int _s = (s);                                                            \
        size_t ko = (size_t)(_s & 15) * BK;                                      \
        size_t eo = ((size_t)(_s >> 4) << 16);  /* 128 rows * 512 elems */       \
        gl_lds16(AbaseS + ko, (AL));                                             \
        gl_lds16(Bbase0 + eo + ko, (BLa));                                       \
        gl_lds16(Bbase1 + eo + ko, (BLb));                                       \
    } while (0)

    // fragment read: same involution as the store side
    const int kchunk = (l4 ^ ((l15 >> 1) & 3)) * 8;   // elements within row
    const ushort* ab0 = As[0] + (wave_m * 32 + l15) * BK + kchunk;
    const ushort* bb0 = Bs[0] + (wave_n * 64 + l15) * BK + kchunk;
    const ushort* ab1 = As[1] + (wave_m * 32 + l15) * BK + kchunk;
    const ushort* bb1 = Bs[1] + (wave_n * 64 + l15) * BK + kchunk;

    f32x4 acc[2][4];

    #define COMPUTE(AB, BB) do {                                                 \
        half8 a_[2], b_[4];                                                      \
        _Pragma("unroll")                                                        \
        for (int mi = 0; mi < 2; mi++) a_[mi] = *(const half8*)((AB) + mi * 16 * BK); \
        _Pragma("unroll")                                                        \
        for (int ni = 0; ni < 4; ni++) b_[ni] = *(const half8*)((BB) + ni * 16 * BK); \
        _Pragma("unroll")                                                        \
        for (int mi = 0; mi < 2; mi++)                                           \
            _Pragma("unroll")                                                    \
            for (int ni = 0; ni < 4; ni++)                                       \
                acc[mi][ni] = __builtin_amdgcn_mfma_f32_16x16x32_f16(a_[mi], b_[ni], acc[mi][ni], 0, 0, 0); \
    } while (0)

    STAGE(0, aL0, bL0a, bL0b);
    __syncthreads();                       // drains vmcnt -> buf0 ready

    for (int e0 = 0; e0 < 16; e0++) {
        #pragma unroll
        for (int mi = 0; mi < 2; mi++)
            #pragma unroll
            for (int ni = 0; ni < 4; ni++)
                acc[mi][ni] = (f32x4){0.f, 0.f, 0.f, 0.f};

        for (int p = 0; p < 8; p++) {
            const int s = e0 * 16 + p * 2;
            STAGE(s + 1, aL1, bL1a, bL1b);   // fill buf1 while computing buf0
            COMPUTE(ab0, bb0);
            __syncthreads();                 // buf1 ready, buf0 reads done
            if (s + 2 < 256) STAGE(s + 2, aL0, bL0a, bL0b);
            COMPUTE(ab1, bb1);
            if (p == 7) {
                // fold: score = wnorm[e] - 2*dot; D: col=lane&15, row=(lane>>4)*4+reg
                #pragma unroll
                for (int ni = 0; ni < 4; ni++) {
                    int col = ebase + e0 * BN + wave_n * 64 + ni * 16 + l15;
                    float wn = wnorm[col];
                    #pragma unroll
                    for (int mi = 0; mi < 2; mi++)
                        #pragma unroll
                        for (int r = 0; r < 4; r++) {
                            float sc = fmaf(-2.0f, acc[mi][ni][r], wn);
                            int q = mi * 4 + r;
                            if (sc < v0[q])      { v1[q] = v0[q]; i1[q] = i0[q]; v0[q] = sc; i0[q] = col; }
                            else if (sc < v1[q]) { v1[q] = sc; i1[q] = col; }
                        }
                }
            }
            __syncthreads();                 // buf0 ready, buf1 reads done
        }
    }

    // 16-lane top2 butterfly (lanes sharing a row), then cross-wave_n merge via LDS
    #pragma unroll
    for (int mi = 0; mi < 2; mi++)
        #pragma unroll
        for (int r = 0; r < 4; r++) {
            int q = mi * 4 + r;
            Top2 T = {v0[q], v1[q], i0[q], i1[q]};
            #pragma unroll
            for (int mk = 1; mk <= 8; mk <<= 1) {
                Top2 O;
                O.v0 = __shfl_xor(T.v0, mk); O.v1 = __shfl_xor(T.v1, mk);
                O.i0 = __shfl_xor(T.i0, mk); O.i1 = __shfl_xor(T.i1, mk);
                T = merge2(T, O);
            }
            if (l15 == 0) {
                int rl = wave_m * 32 + mi * 16 + l4 * 4 + r;
                SmTop[rl][wave_n] = make_float4(T.v0, __int_as_float(T.i0), T.v1, __int_as_float(T.i1));
            }
        }
    __syncthreads();
    if (t < BM) {
        float4 Fa = SmTop[t][0], Fb = SmTop[t][1];
        Top2 A2 = {Fa.x, Fa.z, __float_as_int(Fa.y), __float_as_int(Fa.w)};
        Top2 B2 = {Fb.x, Fb.z, __float_as_int(Fb.y), __float_as_int(Fb.w)};
        Top2 T = merge2(A2, B2);
        cand[(size_t)(row0 + t) * (2 * NQ) + quarter * 2 + 0] = T.i0;
        cand[(size_t)(row0 + t) * (2 * NQ) + quarter * 2 + 1] = T.i1;
    }
    #undef STAGE
    #undef COMPUTE
}

// ---------------- fp32 rescore of 8 candidates + gather z_q + loss partial ----------------
__global__ __launch_bounds__(256) void rescore_gather_loss(
        const float* __restrict__ Z, const float* __restrict__ W,
        const float* __restrict__ wnorm, const int* __restrict__ cand,
        float* __restrict__ out, float* __restrict__ partials) {
    const int n = blockIdx.x;
    const int t = threadIdx.x;
    const int lane = t & 63, wv = t >> 6;
    int c[8];
    #pragma unroll
    for (int j = 0; j < 8; j++) c[j] = cand[(size_t)n * 8 + j];
    float2 zv = ((const float2*)(Z + (size_t)n * E_DIM))[t];
    float2 wvv[8];
    #pragma unroll
    for (int j = 0; j < 8; j++)
        wvv[j] = ((const float2*)(W + (size_t)c[j] * E_DIM))[t];
    __shared__ float red[4][8];
    #pragma unroll
    for (int j = 0; j < 8; j++) {
        float s = zv.x * wvv[j].x + zv.y * wvv[j].y;
        #pragma unroll
        for (int off = 32; off; off >>= 1) s += __shfl_down(s, off);
        if (lane == 0) red[wv][j] = s;
    }
    __syncthreads();
    float best = FLT_MAX; int bj = 0, bc = 0x7fffffff;
    #pragma unroll
    for (int j = 0; j < 8; j++) {
        float d = red[0][j] + red[1][j] + red[2][j] + red[3][j];
        float s = wnorm[c[j]] - 2.0f * d;
        if (s < best || (s == best && c[j] < bc)) { best = s; bj = j; bc = c[j]; }
    }
    float2 wq = wvv[0];                 // static-index select (rule #20)
    #pragma unroll
    for (int j = 1; j < 8; j++) if (bj == j) wq = wvv[j];
    ((float2*)(out + 1 + (size_t)n * E_DIM))[t] = wq;   // z_q_st == z_q numerically
    float d0 = wq.x - zv.x, d1 = wq.y - zv.y;
    float sl = d0 * d0 + d1 * d1;
    #pragma unroll
    for (int off = 32; off; off >>= 1) sl += __shfl_down(sl, off);
    __shared__ float red2[4];
    if (lane == 0) red2[wv] = sl;
    __syncthreads();
    if (t == 0) {
        partials[n] = red2[0] + red2[1] + red2[2] + red2[3];
        out[1 + (size_t)M_ROWS * E_DIM + n] = (float)bc;
    }
}

// ---------------- deterministic final loss reduction ----------------
__global__ __launch_bounds__(256) void loss_reduce_kernel(const float* __restrict__ partials,
                                                          float* __restrict__ out) {
    const int t = threadIdx.x;
    float s = 0.0f;
    for (int i = t; i < M_ROWS; i += 256) s += partials[i];
    #pragma unroll
    for (int off = 32; off; off >>= 1) s += __shfl_down(s, off);
    __shared__ float red[4];
    if ((t & 63) == 0) red[t >> 6] = s;
    __syncthreads();
    if (t == 0) {
        float total = red[0] + red[1] + red[2] + red[3];
        out[0] = 2.0f * total / ((float)M_ROWS * (float)E_DIM);  // beta=1 collapses
    }
}

extern "C" void kernel_launch(void* const* d_in, const int* in_sizes, int n_in,
                              void* d_out, int out_size, void* d_ws, size_t ws_size,
                              hipStream_t stream) {
    const float* Z = (const float*)d_in[0];
    const float* W = (const float*)d_in[1];
    float* out = (float*)d_out;

    char* p = (char*)d_ws;
    ushort* Zh = (ushort*)p;      p += (size_t)M_ROWS * E_DIM * 2;
    ushort* Wh = (ushort*)p;      p += (size_t)N_E * E_DIM * 2;
    float* wnorm = (float*)p;     p += (size_t)N_E * 4;
    int* cand = (int*)p;          p += (size_t)M_ROWS * 8 * 4;
    float* partials = (float*)p;  p += (size_t)M_ROWS * 4;

    f16_cast_kernel<<<(M_ROWS * E_DIM / 4 + 255) / 256, 256, 0, stream>>>(Z, Zh, M_ROWS * E_DIM / 4);
    f16_cast_kernel<<<(N_E * E_DIM / 4 + 255) / 256, 256, 0, stream>>>(W, Wh, N_E * E_DIM / 4);
    wnorm_kernel<<<N_E / 4, 256, 0, stream>>>(W, wnorm);
    argmin_mfma<<<NQ * (M_ROWS / BM), 256, 0, stream>>>(Zh, Wh, wnorm, cand);
    rescore_gather_loss<<<M_ROWS, 256, 0, stream>>>(Z, W, wnorm, cand, out, partials);
    loss_reduce_kernel<<<1, 256, 0, stream>>>(partials, out);
}

// Round 7
// 796.785 us; speedup vs baseline: 1.4422x; 1.1447x over previous
//
#include <hip/hip_runtime.h>
#include <hip/hip_fp16.h>
#include <float.h>

#define M_ROWS 32768
#define E_DIM  512
#define N_E    8192

#define BM 64
#define BN 128
#define BK 32
#define NQ 4                    // quarters of the e-range
#define EQ (N_E / NQ)           // 2048 codes per quarter
#define SLOT_BYTES 12288        // A 4KB + B 8KB per K-step slot

typedef __attribute__((ext_vector_type(8))) _Float16 half8;
typedef __attribute__((ext_vector_type(4))) float f32x4;

__device__ inline void gl_lds16(const void* g, void* l) {
    __builtin_amdgcn_global_load_lds(
        (const __attribute__((address_space(1))) unsigned int*)g,
        (__attribute__((address_space(3))) unsigned int*)l, 16, 0, 0);
}

// ---------------- fp32 -> fp16 (RTNE) ----------------
__global__ __launch_bounds__(256) void f16_cast_kernel(const float* __restrict__ X,
                                                       ushort* __restrict__ H,
                                                       int n4) {
    int i = blockIdx.x * 256 + threadIdx.x;
    if (i >= n4) return;
    float4 v = ((const float4*)X)[i];
    float c[4] = {v.x, v.y, v.z, v.w};
    ushort hh[4];
    #pragma unroll
    for (int j = 0; j < 4; j++) {
        __half hb = __float2half(c[j]);
        hh[j] = *(ushort*)&hb;
    }
    ushort4 h = {hh[0], hh[1], hh[2], hh[3]};
    ((ushort4*)H)[i] = h;
}

// ---------------- wnorm[e] = sum_k W[e][k]^2 (fp32, exact) ----------------
__global__ __launch_bounds__(256) void wnorm_kernel(const float* __restrict__ W,
                                                    float* __restrict__ wnorm) {
    int wave_id = (int)((blockIdx.x * blockDim.x + threadIdx.x) >> 6);
    int lane = threadIdx.x & 63;
    if (wave_id >= N_E) return;
    const float* row = W + (size_t)wave_id * E_DIM;
    float4 v0 = *(const float4*)(row + lane * 4);
    float4 v1 = *(const float4*)(row + 256 + lane * 4);
    float s = v0.x*v0.x + v0.y*v0.y + v0.z*v0.z + v0.w*v0.w
            + v1.x*v1.x + v1.y*v1.y + v1.z*v1.z + v1.w*v1.w;
    #pragma unroll
    for (int off = 32; off; off >>= 1) s += __shfl_down(s, off);
    if (lane == 0) wnorm[wave_id] = s;
}

struct Top2 { float v0, v1; int i0, i1; };

__device__ inline Top2 merge2(Top2 A, Top2 B) {
    bool af = (A.v0 < B.v0) || (A.v0 == B.v0 && A.i0 < B.i0);
    float Wv1 = af ? A.v1 : B.v1; int Wi1 = af ? A.i1 : B.i1;
    float Lv0 = af ? B.v0 : A.v0; int Li0 = af ? B.i0 : A.i0;
    bool s2 = (Wv1 < Lv0) || (Wv1 == Lv0 && Wi1 < Li0);
    Top2 R;
    R.v0 = af ? A.v0 : B.v0; R.i0 = af ? A.i0 : B.i0;
    R.v1 = s2 ? Wv1 : Lv0;   R.i1 = s2 ? Wi1 : Li0;
    return R;
}

// ---------------- fp16 MFMA screen (K=512) + per-row top-2 per QUARTER ----------------
// Screen semantics identical to the PASSING R4/R6 config. Execution change (T3+T4):
// 4-deep LDS slot pipeline with COUNTED vmcnt -- one s_barrier per K-step, never
// vmcnt(0) in the main loop. Step i: vmcnt(6); barrier; stage(i+3); read slot i&3;
// MFMA (setprio-wrapped); fold at e0-tile end. stage(i) was issued 3 steps ago and
// every wave executes vmcnt(6) (= allow stage(i+1),stage(i+2) in flight) before
// the barrier, so slot i is globally ready. Slot (i+3)&3 was consumed at step i-1,
// confirmed by barrier(i). Tail peeled with vmcnt(6)/(3)/(0).
__global__ __launch_bounds__(256, 2) void argmin_mfma(
        const ushort* __restrict__ Zh, const ushort* __restrict__ Wh,
        const float* __restrict__ wnorm, int* __restrict__ cand) {
    __shared__ __align__(16) char Lds[4][SLOT_BYTES];   // 48 KB
    __shared__ float4 SmTop[BM][2];                     // 2 KB

    const int t = threadIdx.x;
    const int lane = t & 63;
    const int wid = t >> 6;            // 0..3
    const int wave_m = wid >> 1;       // 0..1 (32-row chunk)
    const int wave_n = wid & 1;        // 0..1 (64-col chunk)
    const int l15 = lane & 15, l4 = lane >> 4;

    // chunked XCD remap (2048 blocks, 8 XCDs, 256-block chunks; bijective).
    const int id = blockIdx.x;
    const int orig = (id & 7) * 256 + (id >> 3);
    const int quarter = orig >> 9;
    const int rowblk = orig & 511;
    const int row0 = rowblk * BM;
    const int ebase = quarter * EQ;

    // staging: A 64x32 = 256 16B-chunks (1/thread), B 128x32 = 512 (2/thread).
    // Swizzle on the GLOBAL side (LDS dest linear, rule #21): k-chunk ^= (row>>1)&3.
    const int srow = t >> 2;
    const int akc = ((t & 3) ^ ((t >> 3) & 3)) * 8;
    const int brow1 = 64 + srow;
    const int bkc1 = ((t & 3) ^ ((brow1 >> 1) & 3)) * 8;
    const ushort* AbaseS = Zh + (size_t)(row0 + srow) * E_DIM + akc;
    const ushort* Bbase0 = Wh + (size_t)(ebase + srow) * E_DIM + akc;
    const ushort* Bbase1 = Wh + (size_t)(ebase + brow1) * E_DIM + bkc1;

    // fragment read offsets (same involution), bytes within a slot
    const int kchunk = (l4 ^ ((l15 >> 1) & 3)) * 8;
    const int a_roff = (wave_m * 32 + l15) * (BK * 2) + kchunk * 2;
    const int b_roff = 4096 + (wave_n * 64 + l15) * (BK * 2) + kchunk * 2;

    // per-thread top2 over 8 row-slots q=mi*4+r; row = wave_m*32+mi*16+l4*4+r
    float v0[8], v1[8];
    int i0[8], i1[8];
    #pragma unroll
    for (int q = 0; q < 8; q++) { v0[q] = FLT_MAX; v1[q] = FLT_MAX; i0[q] = 0; i1[q] = 0; }

    f32x4 acc[2][4];
    #pragma unroll
    for (int mi = 0; mi < 2; mi++)
        #pragma unroll
        for (int ni = 0; ni < 4; ni++)
            acc[mi][ni] = (f32x4){0.f, 0.f, 0.f, 0.f};

    // step s in [0,256): e0-tile = s>>4 (128 codes), k-step = s&15
    #define STAGE(s) do {                                                        \
        int _s = (s);                                                            \
        char* _sl = Lds[_s & 3];                                                 \
        size_t ko = (size_t)(_s & 15) * BK;                                      \
        size_t eo = ((size_t)(_s >> 4) << 16);  /* 128 rows * 512 elems */       \
        gl_lds16(AbaseS + ko, _sl + t * 16);                                     \
        gl_lds16(Bbase0 + eo + ko, _sl + 4096 + t * 16);                         \
        gl_lds16(Bbase1 + eo + ko, _sl + 8192 + t * 16);                         \
    } while (0)

    #define FOLD(E0) do {                                                        \
        _Pragma("unroll")                                                        \
        for (int ni = 0; ni < 4; ni++) {                                         \
            int col = ebase + (E0) * BN + wave_n * 64 + ni * 16 + l15;           \
            float wn = wnorm[col];                                               \
            _Pragma("unroll")                                                    \
            for (int mi = 0; mi < 2; mi++)                                       \
                _Pragma("unroll")                                                \
                for (int r = 0; r < 4; r++) {                                    \
                    float sc = fmaf(-2.0f, acc[mi][ni][r], wn);                  \
                    int q = mi * 4 + r;                                          \
                    if (sc < v0[q])      { v1[q] = v0[q]; i1[q] = i0[q]; v0[q] = sc; i0[q] = col; } \
                    else if (sc < v1[q]) { v1[q] = sc; i1[q] = col; }            \
                }                                                                \
        }                                                                        \
        _Pragma("unroll")                                                        \
        for (int mi = 0; mi < 2; mi++)                                           \
            _Pragma("unroll")                                                    \
            for (int ni = 0; ni < 4; ni++)                                       \
                acc[mi][ni] = (f32x4){0.f, 0.f, 0.f, 0.f};                       \
    } while (0)

    #define STEP(i, VMSTR, DO_STAGE) do {                                        \
        asm volatile("s_waitcnt " VMSTR ::: "memory");                           \
        __builtin_amdgcn_s_barrier();                                            \
        __builtin_amdgcn_sched_barrier(0);                                       \
        if (DO_STAGE) STAGE((i) + 3);                                            \
        const char* _sl = Lds[(i) & 3];                                          \
        const ushort* _ab = (const ushort*)(_sl + a_roff);                       \
        const ushort* _bb = (const ushort*)(_sl + b_roff);                       \
        half8 a_[2], b_[4];                                                      \
        _Pragma("unroll")                                                        \
        for (int mi = 0; mi < 2; mi++) a_[mi] = *(const half8*)(_ab + mi * 16 * BK); \
        _Pragma("unroll")                                                        \
        for (int ni = 0; ni < 4; ni++) b_[ni] = *(const half8*)(_bb + ni * 16 * BK); \
        __builtin_amdgcn_s_setprio(1);                                           \
        _Pragma("unroll")                                                        \
        for (int mi = 0; mi < 2; mi++)                                           \
            _Pragma("unroll")                                                    \
            for (int ni = 0; ni < 4; ni++)                                       \
                acc[mi][ni] = __builtin_amdgcn_mfma_f32_16x16x32_f16(a_[mi], b_[ni], acc[mi][ni], 0, 0, 0); \
        __builtin_amdgcn_s_setprio(0);                                           \
        if (((i) & 15) == 15) FOLD((i) >> 4);                                    \
    } while (0)

    STAGE(0); STAGE(1); STAGE(2);
    for (int i = 0; i < 253; ++i) STEP(i, "vmcnt(6)", true);
    STEP(253, "vmcnt(6)", false);
    STEP(254, "vmcnt(3)", false);
    STEP(255, "vmcnt(0)", false);

    // 16-lane top2 butterfly (lanes sharing a row), then cross-wave_n merge via LDS
    #pragma unroll
    for (int mi = 0; mi < 2; mi++)
        #pragma unroll
        for (int r = 0; r < 4; r++) {
            int q = mi * 4 + r;
            Top2 T = {v0[q], v1[q], i0[q], i1[q]};
            #pragma unroll
            for (int mk = 1; mk <= 8; mk <<= 1) {
                Top2 O;
                O.v0 = __shfl_xor(T.v0, mk); O.v1 = __shfl_xor(T.v1, mk);
                O.i0 = __shfl_xor(T.i0, mk); O.i1 = __shfl_xor(T.i1, mk);
                T = merge2(T, O);
            }
            if (l15 == 0) {
                int rl = wave_m * 32 + mi * 16 + l4 * 4 + r;
                SmTop[rl][wave_n] = make_float4(T.v0, __int_as_float(T.i0), T.v1, __int_as_float(T.i1));
            }
        }
    __syncthreads();
    if (t < BM) {
        float4 Fa = SmTop[t][0], Fb = SmTop[t][1];
        Top2 A2 = {Fa.x, Fa.z, __float_as_int(Fa.y), __float_as_int(Fa.w)};
        Top2 B2 = {Fb.x, Fb.z, __float_as_int(Fb.y), __float_as_int(Fb.w)};
        Top2 T = merge2(A2, B2);
        cand[(size_t)(row0 + t) * (2 * NQ) + quarter * 2 + 0] = T.i0;
        cand[(size_t)(row0 + t) * (2 * NQ) + quarter * 2 + 1] = T.i1;
    }
    #undef STAGE
    #undef FOLD
    #undef STEP
}

// ---------------- fp32 rescore of 8 candidates + gather z_q + loss partial ----------------
__global__ __launch_bounds__(256) void rescore_gather_loss(
        const float* __restrict__ Z, const float* __restrict__ W,
        const float* __restrict__ wnorm, const int* __restrict__ cand,
        float* __restrict__ out, float* __restrict__ partials) {
    const int n = blockIdx.x;
    const int t = threadIdx.x;
    const int lane = t & 63, wv = t >> 6;
    int c[8];
    #pragma unroll
    for (int j = 0; j < 8; j++) c[j] = cand[(size_t)n * 8 + j];
    float2 zv = ((const float2*)(Z + (size_t)n * E_DIM))[t];
    float2 wvv[8];
    #pragma unroll
    for (int j = 0; j < 8; j++)
        wvv[j] = ((const float2*)(W + (size_t)c[j] * E_DIM))[t];
    __shared__ float red[4][8];
    #pragma unroll
    for (int j = 0; j < 8; j++) {
        float s = zv.x * wvv[j].x + zv.y * wvv[j].y;
        #pragma unroll
        for (int off = 32; off; off >>= 1) s += __shfl_down(s, off);
        if (lane == 0) red[wv][j] = s;
    }
    __syncthreads();
    float best = FLT_MAX; int bj = 0, bc = 0x7fffffff;
    #pragma unroll
    for (int j = 0; j < 8; j++) {
        float d = red[0][j] + red[1][j] + red[2][j] + red[3][j];
        float s = wnorm[c[j]] - 2.0f * d;
        if (s < best || (s == best && c[j] < bc)) { best = s; bj = j; bc = c[j]; }
    }
    float2 wq = wvv[0];                 // static-index select (rule #20)
    #pragma unroll
    for (int j = 1; j < 8; j++) if (bj == j) wq = wvv[j];
    ((float2*)(out + 1 + (size_t)n * E_DIM))[t] = wq;   // z_q_st == z_q numerically
    float d0 = wq.x - zv.x, d1 = wq.y - zv.y;
    float sl = d0 * d0 + d1 * d1;
    #pragma unroll
    for (int off = 32; off; off >>= 1) sl += __shfl_down(sl, off);
    __shared__ float red2[4];
    if (lane == 0) red2[wv] = sl;
    __syncthreads();
    if (t == 0) {
        partials[n] = red2[0] + red2[1] + red2[2] + red2[3];
        out[1 + (size_t)M_ROWS * E_DIM + n] = (float)bc;
    }
}

// ---------------- deterministic final loss reduction ----------------
__global__ __launch_bounds__(256) void loss_reduce_kernel(const float* __restrict__ partials,
                                                          float* __restrict__ out) {
    const int t = threadIdx.x;
    float s = 0.0f;
    for (int i = t; i < M_ROWS; i += 256) s += partials[i];
    #pragma unroll
    for (int off = 32; off; off >>= 1) s += __shfl_down(s, off);
    __shared__ float red[4];
    if ((t & 63) == 0) red[t >> 6] = s;
    __syncthreads();
    if (t == 0) {
        float total = red[0] + red[1] + red[2] + red[3];
        out[0] = 2.0f * total / ((float)M_ROWS * (float)E_DIM);  // beta=1 collapses
    }
}

extern "C" void kernel_launch(void* const* d_in, const int* in_sizes, int n_in,
                              void* d_out, int out_size, void* d_ws, size_t ws_size,
                              hipStream_t stream) {
    const float* Z = (const float*)d_in[0];
    const float* W = (const float*)d_in[1];
    float* out = (float*)d_out;

    char* p = (char*)d_ws;
    ushort* Zh = (ushort*)p;      p += (size_t)M_ROWS * E_DIM * 2;
    ushort* Wh = (ushort*)p;      p += (size_t)N_E * E_DIM * 2;
    float* wnorm = (float*)p;     p += (size_t)N_E * 4;
    int* cand = (int*)p;          p += (size_t)M_ROWS * 8 * 4;
    float* partials = (float*)p;  p += (size_t)M_ROWS * 4;

    f16_cast_kernel<<<(M_ROWS * E_DIM / 4 + 255) / 256, 256, 0, stream>>>(Z, Zh, M_ROWS * E_DIM / 4);
    f16_cast_kernel<<<(N_E * E_DIM / 4 + 255) / 256, 256, 0, stream>>>(W, Wh, N_E * E_DIM / 4);
    wnorm_kernel<<<N_E / 4, 256, 0, stream>>>(W, wnorm);
    argmin_mfma<<<NQ * (M_ROWS / BM), 256, 0, stream>>>(Zh, Wh, wnorm, cand);
    rescore_gather_loss<<<M_ROWS, 256, 0, stream>>>(Z, W, wnorm, cand, out, partials);
    loss_reduce_kernel<<<1, 256, 0, stream>>>(partials, out);
}